// Round 19
// baseline (123.630 us; speedup 1.0000x reference)
//
#include <hip/hip_runtime.h>
#include <hip/hip_bf16.h>
#include <stdint.h>

// Problem dims (fixed)
#define MD    1024      // model dim
#define NHEAD 16
#define HDIM  64
#define BSZ   2
#define SEQL  2048
#define MROWS 4096      // BSZ*SEQL

#define SCL2E 0.18033688011112042f   // (1/sqrt(64)) * log2(e), folded into Wq/bq

typedef __bf16 bf16_t;
typedef __bf16  bf16x8 __attribute__((ext_vector_type(8)));
typedef float   f32x4  __attribute__((ext_vector_type(4)));
typedef float   f32x16 __attribute__((ext_vector_type(16)));

// raw v_exp_f32 via compiler-visible builtin (hazards handled by backend).
// R16's inline-asm version FAILED (absmax 5.5e-2): MFMA->TRANS wait-states
// aren't guaranteed across an asm boundary (rule #18). R17/R18 proved the
// builtin correct AND fast (attn 60.2 -> 48.2us).
#if __has_builtin(__builtin_amdgcn_exp2f)
  #define FEXP2(x) __builtin_amdgcn_exp2f(x)
#else
  #define FEXP2(x) exp2f(x)
#endif

// Async global->LDS, 16B per lane. LDS dest is wave-uniform base (+lane*16 by HW).
__device__ __forceinline__ void gload_lds16(const void* g, void* l) {
  __builtin_amdgcn_global_load_lds((const __attribute__((address_space(1))) void*)g,
                                   (__attribute__((address_space(3))) void*)l,
                                   16, 0, 0);
}

__device__ __forceinline__ unsigned short f2bf(float f) {
  unsigned u = __builtin_bit_cast(unsigned, f);
  u += 0x7fffu + ((u >> 16) & 1u);          // round-to-nearest-even
  return (unsigned short)(u >> 16);
}

// packed 2xf32 -> 2xbf16 in one dword (src0 -> low half)
__device__ __forceinline__ unsigned cvtpk(float a, float b) {
  unsigned r;
  asm("v_cvt_pk_bf16_f32 %0, %1, %2" : "=v"(r) : "v"(a), "v"(b));
  return r;
}

// ---------------- consolidated convert ----------------
// grid 16387: [0,12288) X (4096 each), [12288,16384) W (1024 each; Wq scaled),
// 16384: bq*SCL2E -> bqs ; 16385/16386: nmask[b] = sum(1-mask[b][:])
__global__ __launch_bounds__(256)
void cvt_all(const float* __restrict__ q, const float* __restrict__ k, const float* __restrict__ v,
             const float* __restrict__ wq, const float* __restrict__ wk,
             const float* __restrict__ wv, const float* __restrict__ wo,
             const float* __restrict__ mask, const float* __restrict__ bq,
             unsigned short* __restrict__ xq, unsigned short* __restrict__ xk, unsigned short* __restrict__ xv,
             unsigned short* __restrict__ wqb, unsigned short* __restrict__ wkb,
             unsigned short* __restrict__ wvb, unsigned short* __restrict__ wob,
             float* __restrict__ bqs, float* __restrict__ nmask) {
  int bx = blockIdx.x;
  if (bx >= 16384) {
    if (bx == 16384) {                    // bqs = bq * SCL2E (1024 floats)
      int i = threadIdx.x;
      float4 val = ((const float4*)bq)[i];
      float4 o;
      o.x = val.x * SCL2E; o.y = val.y * SCL2E; o.z = val.z * SCL2E; o.w = val.w * SCL2E;
      ((float4*)bqs)[i] = o;
    } else {                              // nmask[b]
      int b = bx - 16385;
      const float* mp = mask + b * SEQL + threadIdx.x * 8;
      float s = 0.0f;
#pragma unroll
      for (int j = 0; j < 8; ++j) s += 1.0f - mp[j];
      for (int d = 1; d < 64; d <<= 1) s += __shfl_xor(s, d);
      __shared__ float wsum[4];
      if ((threadIdx.x & 63) == 0) wsum[threadIdx.x >> 6] = s;
      __syncthreads();
      if (threadIdx.x == 0) nmask[b] = wsum[0] + wsum[1] + wsum[2] + wsum[3];
    }
    return;
  }
  const float* in; unsigned short* out; int i;
  float scale = 1.0f;
  if (bx < 12288) {
    int t = bx >> 12;
    in  = (t == 0) ? q : (t == 1) ? k : v;
    out = (t == 0) ? xq : (t == 1) ? xk : xv;
    i = (bx & 4095) * 256 + threadIdx.x;
  } else {
    int t = (bx - 12288) >> 10;
    in  = (t == 0) ? wq : (t == 1) ? wk : (t == 2) ? wv : wo;
    out = (t == 0) ? wqb : (t == 1) ? wkb : (t == 2) ? wvb : wob;
    if (t == 0) scale = SCL2E;
    i = (bx & 1023) * 256 + threadIdx.x;
  }
  float4 val = ((const float4*)in)[i];
  ushort4 o;
  o.x = f2bf(val.x * scale); o.y = f2bf(val.y * scale);
  o.z = f2bf(val.z * scale); o.w = f2bf(val.w * scale);
  ((ushort4*)out)[i] = o;
}

// ---------------- GEMM: C[m,n] = sum_k A[m,k]*B[n,k] + bias[n] ----------------
// 128x128 tile, BK=64, 4 waves (2x2 of 64x64), 16x16x32 bf16 MFMA.
// SHARED BUFFER IS PASSED IN (declared once per kernel!) — 3 template
// instantiations in one kernel would otherwise each get their own static
// 32KB LDS (R13: LDS_Block_Size=98304 -> 1 block/CU -> 70us).
// MODE: 0 = bf16 row-major [m][n], optional runtime row-mask;
//       1 = f32 row-major;
//       2 = bf16 V in PV(32x32x16) B-frag layout, row-masked;
//       3 = bf16 K in QKt(32x32x16) A-frag layout, row-masked.
template<int MODE>
__device__ __forceinline__ void gemm_body(char* __restrict__ sm,
                                          const bf16_t* __restrict__ A,
                                          const bf16_t* __restrict__ Bm,
                                          const float*  __restrict__ bias,
                                          const float*  __restrict__ mask,
                                          void* __restrict__ Cout, int tile) {
  char* lsA = sm;
  char* lsB = sm + 16384;
  const int tid  = threadIdx.x;
  const int lane = tid & 63;
  const int wv   = tid >> 6;
  const int wm   = wv >> 1, wn = wv & 1;
  const int m0   = (tile >> 3) << 7;   // 32 m-tiles
  const int n0   = (tile & 7)  << 7;   // 8 n-tiles
  const int l15  = lane & 15;
  const int g16  = (lane >> 4) << 4;   // k-group byte base

  f32x4 acc[4][4] = {};

  for (int kk = 0; kk < MD; kk += 64) {
#pragma unroll
    for (int i = 0; i < 4; ++i) {
      int ch  = (wv << 2) + i;
      int o   = ch * 1024 + (lane << 4);
      int row = o >> 7;
      int scb = (o & 127) ^ ((row & 7) << 4);   // pre-swizzled source column byte
      const char* gA = (const char*)A  + (((size_t)(m0 + row) * MD + kk) << 1) + scb;
      const char* gB = (const char*)Bm + (((size_t)(n0 + row) * MD + kk) << 1) + scb;
      gload_lds16(gA, lsA + ch * 1024);
      gload_lds16(gB, lsB + ch * 1024);
    }
    __syncthreads();
#pragma unroll
    for (int s = 0; s < 2; ++s) {
      bf16x8 af[4], bfv[4];
#pragma unroll
      for (int mi = 0; mi < 4; ++mi) {
        int r  = (wm << 6) + (mi << 4) + l15;
        int cb = (g16 + (s << 6)) ^ ((r & 7) << 4);
        af[mi] = *(const bf16x8*)(lsA + (r << 7) + cb);
      }
#pragma unroll
      for (int ni = 0; ni < 4; ++ni) {
        int r  = (wn << 6) + (ni << 4) + l15;
        int cb = (g16 + (s << 6)) ^ ((r & 7) << 4);
        bfv[ni] = *(const bf16x8*)(lsB + (r << 7) + cb);
      }
      __builtin_amdgcn_s_setprio(1);
#pragma unroll
      for (int mi = 0; mi < 4; ++mi)
#pragma unroll
        for (int ni = 0; ni < 4; ++ni)
          acc[mi][ni] = __builtin_amdgcn_mfma_f32_16x16x32_bf16(af[mi], bfv[ni], acc[mi][ni], 0, 0, 0);
      __builtin_amdgcn_s_setprio(0);
    }
    __syncthreads();
  }

  // epilogue: C/D layout col = lane&15, row = (lane>>4)*4 + reg
  float bvv[4];
#pragma unroll
  for (int ni = 0; ni < 4; ++ni) bvv[ni] = bias[n0 + (wn << 6) + (ni << 4) + l15];
#pragma unroll
  for (int mi = 0; mi < 4; ++mi) {
    int m = m0 + (wm << 6) + (mi << 4) + ((lane >> 4) << 2);  // token rows m..m+3
    float4 mk = {1.0f, 1.0f, 1.0f, 1.0f};
    if constexpr (MODE == 2 || MODE == 3) mk = *(const float4*)&mask[m];
    if constexpr (MODE == 0) { if (mask) mk = *(const float4*)&mask[m]; }
#pragma unroll
    for (int ni = 0; ni < 4; ++ni) {
      int col = n0 + (wn << 6) + (ni << 4) + l15;
      if constexpr (MODE == 2) {
        // V PV-B-frag layout; 4 consecutive kv -> 4 contiguous elems (8B store)
        int b2 = m >> 11; int kv = m & 2047;
        int hh = col >> 6; int dd = col & 63;
        int dl = (dd >> 5) & 1; int dcol = dd & 31;
        size_t base = (size_t)((b2 << 4) + hh) * 131072 + (size_t)(kv >> 5) * 2048
                    + (size_t)((((kv >> 4) & 1) << 1) + dl) * 512
                    + (size_t)((((kv >> 3) & 1) << 5) + dcol) * 8 + (kv & 7);
        ushort4 pk;
        pk.x = f2bf((acc[mi][ni][0] + bvv[ni]) * mk.x);
        pk.y = f2bf((acc[mi][ni][1] + bvv[ni]) * mk.y);
        pk.z = f2bf((acc[mi][ni][2] + bvv[ni]) * mk.z);
        pk.w = f2bf((acc[mi][ni][3] + bvv[ni]) * mk.w);
        *(ushort4*)((unsigned short*)Cout + base) = pk;
      } else if constexpr (MODE == 3) {
        // K QKt-A-frag layout; 4 consecutive kv -> stride-8 scalar stores
        int b2 = m >> 11; int kv = m & 2047;
        int hh = col >> 6; int dd = col & 63;
        size_t base = (size_t)((b2 << 4) + hh) * 131072 + (size_t)(kv >> 5) * 2048
                    + (size_t)(dd >> 4) * 512
                    + (size_t)((((dd >> 3) & 1) << 5) + (kv & 31)) * 8 + (dd & 7);
#pragma unroll
        for (int r = 0; r < 4; ++r)
          ((unsigned short*)Cout)[base + ((size_t)r << 3)] =
              f2bf((acc[mi][ni][r] + bvv[ni]) * ((const float*)&mk)[r]);
      } else {
#pragma unroll
        for (int r = 0; r < 4; ++r) {
          float vv = acc[mi][ni][r] + bvv[ni];
          if constexpr (MODE == 0) vv *= ((const float*)&mk)[r];
          if constexpr (MODE == 1) ((float*)Cout)[(size_t)(m + r) * MD + col] = vv;
          else                     ((bf16_t*)Cout)[(size_t)(m + r) * MD + col] = (bf16_t)vv;
        }
      }
    }
  }
}

// fused QKV (768 blocks = 3/CU): Q row-major pre-scaled; K -> Kf frags; V -> Vf frags.
// ONE shared buffer for all three instantiations (32KB total).
__global__ __launch_bounds__(256, 3)
void gemm_qkv(const bf16_t* __restrict__ xq, const bf16_t* __restrict__ xk, const bf16_t* __restrict__ xv,
              const bf16_t* __restrict__ wq, const bf16_t* __restrict__ wk, const bf16_t* __restrict__ wv_,
              const float* __restrict__ bqs, const float* __restrict__ bk, const float* __restrict__ bv,
              const float* __restrict__ mask,
              bf16_t* __restrict__ Qo, bf16_t* __restrict__ Kfo, bf16_t* __restrict__ Vfo) {
  __shared__ __align__(1024) char sm[32768];
  int t = blockIdx.x & 255;
  int g = blockIdx.x >> 8;
  if (g == 0)      gemm_body<0>(sm, xq, wq,  bqs, nullptr, Qo,  t);
  else if (g == 1) gemm_body<3>(sm, xk, wk,  bk,  mask,    Kfo, t);
  else             gemm_body<2>(sm, xv, wv_, bv,  mask,    Vfo, t);
}

__global__ __launch_bounds__(256, 2)
void gemm_out(const bf16_t* __restrict__ A, const bf16_t* __restrict__ Bm,
              const float* __restrict__ bias, float* __restrict__ C) {
  __shared__ __align__(1024) char sm[32768];
  gemm_body<1>(sm, A, Bm, bias, nullptr, C, (int)blockIdx.x);
}

// ---------------- flash attention: all-fragment 32x32, 2-chunk pipeline -----
// grid 512 = b(2)*h(16)*qtile(16 of 128q), XCD swizzle; block 256 = 4 waves,
// each wave owns 32 q and sweeps ALL kv in 64 chunks of 32 (convoyed waves
// share L1). Per iteration, TWO chunks (A,B) explicitly interleaved:
// QKT(A); QKT(B)  <- 8 independent MFMAs fill the sacc latency window
// exp/pack(A); PV(A); exp/pack(B) overlaps PV(A)'s MFMAs; PV(B).
// Next-chunk loads issued right after each operand's last read.
// Swapped QK^T: softmax lane-local (no-max builtin v_exp_f32, deferred
// reduce). P assembled in regs via cvt_pk + permlane32_swap.
__global__ __launch_bounds__(256, 2)
void attn_kernel(const bf16_t* __restrict__ Q, const bf16_t* __restrict__ Kf,
                 const bf16_t* __restrict__ Vf, const float* __restrict__ nmask,
                 bf16_t* __restrict__ O) {
  int bid = (int)blockIdx.x;
  int lb  = (bid & 7) * 64 + (bid >> 3);   // 512 = 8 x 64, bijective
  const int tid  = threadIdx.x;
  const int lane = tid & 63;
  const int w    = tid >> 6;
  const int qt   = lb & 15;
  const int h    = (lb >> 4) & 15;
  const int b    = lb >> 8;
  const int q0w  = (qt << 7) + (w << 5);
  const int l31  = lane & 31;
  const int hi   = lane >> 5;

  // Q B-frags: lane holds Q[q=l31][d = s4*16 + hi*8 + j]
  bf16x8 qa[4];
  {
    const bf16_t* qp = Q + (size_t)(b * SEQL + q0w + l31) * MD + h * HDIM + (hi << 3);
#pragma unroll
    for (int s4 = 0; s4 < 4; ++s4) qa[s4] = *(const bf16x8*)(qp + (s4 << 4));
  }

  const bf16_t* KfB = Kf + (size_t)((b << 4) + h) * 131072;
  const bf16_t* VfB = Vf + (size_t)((b << 4) + h) * 131072;

  f32x16 oacc0 = {};   // d 0-31
  f32x16 oacc1 = {};   // d 32-63
  float lrun = 0.0f;

  bf16x8 kA[4], vA[4], kB[4], vB[4];

  auto LDK = [&](int c, bf16x8* kf) {
    const bf16_t* kp = KfB + (size_t)c * 2048 + (lane << 3);
#pragma unroll
    for (int s4 = 0; s4 < 4; ++s4) kf[s4] = *(const bf16x8*)(kp + (s4 << 9));
  };
  auto LDV = [&](int c, bf16x8* vf) {
    const bf16_t* vp = VfB + (size_t)c * 2048 + (lane << 3);
#pragma unroll
    for (int u = 0; u < 4; ++u) vf[u] = *(const bf16x8*)(vp + (u << 9));
  };

  // softmax + pack for one chunk: sacc -> p0/p1 PV A-frags
  auto SMPK = [&](f32x16& sacc, bf16x8& pv0, bf16x8& pv1) {
    float e[16];
#pragma unroll
    for (int r = 0; r < 16; ++r) e[r] = FEXP2(sacc[r]);
    lrun += ((e[0] + e[1]) + (e[2] + e[3])) + ((e[4] + e[5]) + (e[6] + e[7]))
          + ((e[8] + e[9]) + (e[10] + e[11])) + ((e[12] + e[13]) + (e[14] + e[15]));
    unsigned x1 = cvtpk(e[0], e[1]),  x2 = cvtpk(e[2], e[3]);
    unsigned y1 = cvtpk(e[4], e[5]),  y2 = cvtpk(e[6], e[7]);
    unsigned z1 = cvtpk(e[8], e[9]),  z2 = cvtpk(e[10], e[11]);
    unsigned w1 = cvtpk(e[12], e[13]), w2 = cvtpk(e[14], e[15]);
    asm("v_permlane32_swap_b32 %0, %1" : "+v"(x1), "+v"(y1));
    asm("v_permlane32_swap_b32 %0, %1" : "+v"(x2), "+v"(y2));
    asm("v_permlane32_swap_b32 %0, %1" : "+v"(z1), "+v"(w1));
    asm("v_permlane32_swap_b32 %0, %1" : "+v"(z2), "+v"(w2));
    union { unsigned u[4]; bf16x8 v; } p0, p1;
    p0.u[0] = x1; p0.u[1] = x2; p0.u[2] = y1; p0.u[3] = y2;
    p1.u[0] = z1; p1.u[1] = z2; p1.u[2] = w1; p1.u[3] = w2;
    pv0 = p0.v; pv1 = p1.v;
  };

  LDK(0, kA); LDV(0, vA);
  LDK(1, kB); LDV(1, vB);

  for (int ii = 0; ii < 32; ++ii) {
    const int cA = (ii << 1), cB = cA + 1;
    // --- QK^T for BOTH chunks (8 independent MFMAs fill latency window) ---
    f32x16 sA = {}, sB = {};
    __builtin_amdgcn_s_setprio(1);
#pragma unroll
    for (int s4 = 0; s4 < 4; ++s4)
      sA = __builtin_amdgcn_mfma_f32_32x32x16_bf16(kA[s4], qa[s4], sA, 0, 0, 0);
#pragma unroll
    for (int s4 = 0; s4 < 4; ++s4)
      sB = __builtin_amdgcn_mfma_f32_32x32x16_bf16(kB[s4], qa[s4], sB, 0, 0, 0);
    __builtin_amdgcn_s_setprio(0);
    if (ii < 31) LDK(cA + 2, kA);          // kA dead; prefetch next pair's A

    // --- softmax+pack A, then PV(A) ---
    bf16x8 pA0, pA1;
    SMPK(sA, pA0, pA1);
    __builtin_amdgcn_s_setprio(1);
    oacc0 = __builtin_amdgcn_mfma_f32_32x32x16_bf16(pA0, vA[0], oacc0, 0, 0, 0);
    oacc1 = __builtin_amdgcn_mfma_f32_32x32x16_bf16(pA0, vA[1], oacc1, 0, 0, 0);
    oacc0 = __builtin_amdgcn_mfma_f32_32x32x16_bf16(pA1, vA[2], oacc0, 0, 0, 0);
    oacc1 = __builtin_amdgcn_mfma_f32_32x32x16_bf16(pA1, vA[3], oacc1, 0, 0, 0);
    __builtin_amdgcn_s_setprio(0);
    if (ii < 31) LDV(cA + 2, vA);          // vA dead

    // --- softmax+pack B (VALU overlaps PV(A) MFMAs), then PV(B) ---
    bf16x8 pB0, pB1;
    SMPK(sB, pB0, pB1);
    __builtin_amdgcn_s_setprio(1);
    oacc0 = __builtin_amdgcn_mfma_f32_32x32x16_bf16(pB0, vB[0], oacc0, 0, 0, 0);
    oacc1 = __builtin_amdgcn_mfma_f32_32x32x16_bf16(pB0, vB[1], oacc1, 0, 0, 0);
    oacc0 = __builtin_amdgcn_mfma_f32_32x32x16_bf16(pB1, vB[2], oacc0, 0, 0, 0);
    oacc1 = __builtin_amdgcn_mfma_f32_32x32x16_bf16(pB1, vB[3], oacc1, 0, 0, 0);
    __builtin_amdgcn_s_setprio(0);
    if (ii < 31) { LDK(cB + 2, kB); LDV(cB + 2, vB); }
  }

  // epilogue: combine hi halves of lrun, normalize, store O (row-major bf16)
  lrun += __shfl_xor(lrun, 32);
  float linv = 1.0f / (lrun - nmask[b]);
#pragma unroll
  for (int r = 0; r < 16; ++r) {
    int q = (r & 3) + ((r >> 2) << 3) + (hi << 2);
    float lr = __shfl(linv, q);
    size_t ro = (size_t)(b * SEQL + q0w + q) * MD + h * HDIM;
    O[ro + l31]      = (bf16_t)(oacc0[r] * lr);
    O[ro + 32 + l31] = (bf16_t)(oacc1[r] * lr);
  }
}

// ---------------- launch ----------------
extern "C" void kernel_launch(void* const* d_in, const int* in_sizes, int n_in,
                              void* d_out, int out_size, void* d_ws, size_t ws_size,
                              hipStream_t stream) {
  const float* in_k = (const float*)d_in[0];
  const float* in_q = (const float*)d_in[1];
  const float* in_v = (const float*)d_in[2];
  const float* mask = (const float*)d_in[3];
  const float* Wq   = (const float*)d_in[4];
  const float* bq   = (const float*)d_in[5];
  const float* Wk   = (const float*)d_in[6];
  const float* bk   = (const float*)d_in[7];
  const float* Wv   = (const float*)d_in[8];
  const float* bv   = (const float*)d_in[9];
  const float* Wo   = (const float*)d_in[10];
  const float* bo   = (const float*)d_in[11];

  const size_t XN = (size_t)MROWS * MD;   // 4,194,304 elems
  const size_t WN = (size_t)MD * MD;      // 1,048,576 elems
  char* w = (char*)d_ws;
  size_t off = 0;
  auto alloc = [&](size_t bytes) { char* p = w + off; off += bytes; return p; };
  bf16_t* xq    = (bf16_t*)alloc(XN * 2);
  bf16_t* xk    = (bf16_t*)alloc(XN * 2);
  bf16_t* xv    = (bf16_t*)alloc(XN * 2);
  bf16_t* wqb   = (bf16_t*)alloc(WN * 2);
  bf16_t* wkb   = (bf16_t*)alloc(WN * 2);
  bf16_t* wvb   = (bf16_t*)alloc(WN * 2);
  bf16_t* wob   = (bf16_t*)alloc(WN * 2);
  bf16_t* Qp    = (bf16_t*)alloc(XN * 2);
  bf16_t* Kfp   = (bf16_t*)alloc(XN * 2 + 8192);   // + pad for prefetch overrun
  bf16_t* Vfp   = (bf16_t*)alloc(XN * 2 + 8192);
  float*  bqs   = (float*)alloc(MD * 4);
  float*  nmask = (float*)alloc(16);
  bf16_t* attn  = xq;  // alias: xq is dead after gemm_qkv
  (void)ws_size;

  // single consolidated convert (3 X + 4 W + bqs + nmask)
  cvt_all<<<16387, 256, 0, stream>>>(in_q, in_k, in_v, Wq, Wk, Wv, Wo, mask, bq,
                                     (unsigned short*)xq, (unsigned short*)xk, (unsigned short*)xv,
                                     (unsigned short*)wqb, (unsigned short*)wkb,
                                     (unsigned short*)wvb, (unsigned short*)wob, bqs, nmask);

  // fused QKV projection; K/V written in MFMA fragment layouts
  gemm_qkv<<<768, 256, 0, stream>>>(xq, xk, xv, wqb, wkb, wvb, bqs, bk, bv, mask, Qp, Kfp, Vfp);

  // flash attention: 512 blocks x 4 waves x 32 q, all-fragment, 2-chunk pipe
  attn_kernel<<<512, 256, 0, stream>>>(Qp, Kfp, Vfp, nmask, attn);

  // output projection -> fp32 d_out
  gemm_out<<<256, 256, 0, stream>>>(attn, wob, bo, (float*)d_out);
}

// Round 20
// 117.912 us; speedup vs baseline: 1.0485x; 1.0485x over previous
//
#include <hip/hip_runtime.h>
#include <hip/hip_bf16.h>
#include <stdint.h>

// Problem dims (fixed)
#define MD    1024      // model dim
#define NHEAD 16
#define HDIM  64
#define BSZ   2
#define SEQL  2048
#define MROWS 4096      // BSZ*SEQL

#define SCL2E 0.18033688011112042f   // (1/sqrt(64)) * log2(e), folded into Wq/bq

typedef __bf16 bf16_t;
typedef __bf16  bf16x8 __attribute__((ext_vector_type(8)));
typedef float   f32x4  __attribute__((ext_vector_type(4)));
typedef float   f32x16 __attribute__((ext_vector_type(16)));

// raw v_exp_f32 via compiler-visible builtin (hazards handled by backend).
// R16's inline-asm version FAILED (absmax 5.5e-2): MFMA->TRANS wait-states
// aren't guaranteed across an asm boundary (rule #18). R17/R18 proved the
// builtin correct AND fast (attn 60.2 -> 48.2us).
#if __has_builtin(__builtin_amdgcn_exp2f)
  #define FEXP2(x) __builtin_amdgcn_exp2f(x)
#else
  #define FEXP2(x) exp2f(x)
#endif

// Async global->LDS, 16B per lane. LDS dest is wave-uniform base (+lane*16 by HW).
__device__ __forceinline__ void gload_lds16(const void* g, void* l) {
  __builtin_amdgcn_global_load_lds((const __attribute__((address_space(1))) void*)g,
                                   (__attribute__((address_space(3))) void*)l,
                                   16, 0, 0);
}

__device__ __forceinline__ unsigned short f2bf(float f) {
  unsigned u = __builtin_bit_cast(unsigned, f);
  u += 0x7fffu + ((u >> 16) & 1u);          // round-to-nearest-even
  return (unsigned short)(u >> 16);
}

// packed 2xf32 -> 2xbf16 in one dword (src0 -> low half)
__device__ __forceinline__ unsigned cvtpk(float a, float b) {
  unsigned r;
  asm("v_cvt_pk_bf16_f32 %0, %1, %2" : "=v"(r) : "v"(a), "v"(b));
  return r;
}

// ---------------- consolidated convert ----------------
// grid 16387: [0,12288) X (4096 each), [12288,16384) W (1024 each; Wq scaled),
// 16384: bq*SCL2E -> bqs ; 16385/16386: nmask[b] = sum(1-mask[b][:])
__global__ __launch_bounds__(256)
void cvt_all(const float* __restrict__ q, const float* __restrict__ k, const float* __restrict__ v,
             const float* __restrict__ wq, const float* __restrict__ wk,
             const float* __restrict__ wv, const float* __restrict__ wo,
             const float* __restrict__ mask, const float* __restrict__ bq,
             unsigned short* __restrict__ xq, unsigned short* __restrict__ xk, unsigned short* __restrict__ xv,
             unsigned short* __restrict__ wqb, unsigned short* __restrict__ wkb,
             unsigned short* __restrict__ wvb, unsigned short* __restrict__ wob,
             float* __restrict__ bqs, float* __restrict__ nmask) {
  int bx = blockIdx.x;
  if (bx >= 16384) {
    if (bx == 16384) {                    // bqs = bq * SCL2E (1024 floats)
      int i = threadIdx.x;
      float4 val = ((const float4*)bq)[i];
      float4 o;
      o.x = val.x * SCL2E; o.y = val.y * SCL2E; o.z = val.z * SCL2E; o.w = val.w * SCL2E;
      ((float4*)bqs)[i] = o;
    } else {                              // nmask[b]
      int b = bx - 16385;
      const float* mp = mask + b * SEQL + threadIdx.x * 8;
      float s = 0.0f;
#pragma unroll
      for (int j = 0; j < 8; ++j) s += 1.0f - mp[j];
      for (int d = 1; d < 64; d <<= 1) s += __shfl_xor(s, d);
      __shared__ float wsum[4];
      if ((threadIdx.x & 63) == 0) wsum[threadIdx.x >> 6] = s;
      __syncthreads();
      if (threadIdx.x == 0) nmask[b] = wsum[0] + wsum[1] + wsum[2] + wsum[3];
    }
    return;
  }
  const float* in; unsigned short* out; int i;
  float scale = 1.0f;
  if (bx < 12288) {
    int t = bx >> 12;
    in  = (t == 0) ? q : (t == 1) ? k : v;
    out = (t == 0) ? xq : (t == 1) ? xk : xv;
    i = (bx & 4095) * 256 + threadIdx.x;
  } else {
    int t = (bx - 12288) >> 10;
    in  = (t == 0) ? wq : (t == 1) ? wk : (t == 2) ? wv : wo;
    out = (t == 0) ? wqb : (t == 1) ? wkb : (t == 2) ? wvb : wob;
    if (t == 0) scale = SCL2E;
    i = (bx & 1023) * 256 + threadIdx.x;
  }
  float4 val = ((const float4*)in)[i];
  ushort4 o;
  o.x = f2bf(val.x * scale); o.y = f2bf(val.y * scale);
  o.z = f2bf(val.z * scale); o.w = f2bf(val.w * scale);
  ((ushort4*)out)[i] = o;
}

// ---------------- GEMM: C[m,n] = sum_k A[m,k]*B[n,k] + bias[n] ----------------
// 128x128 tile, BK=64, 4 waves (2x2 of 64x64), 16x16x32 bf16 MFMA.
// SHARED BUFFER IS PASSED IN (declared once per kernel!) — 3 template
// instantiations in one kernel would otherwise each get their own static
// 32KB LDS (R13: LDS_Block_Size=98304 -> 1 block/CU -> 70us).
// MODE: 0 = bf16 row-major [m][n], optional runtime row-mask;
//       1 = f32 row-major;
//       2 = bf16 V in PV(32x32x16) B-frag layout, row-masked;
//       3 = bf16 K in QKt(32x32x16) A-frag layout, row-masked.
template<int MODE>
__device__ __forceinline__ void gemm_body(char* __restrict__ sm,
                                          const bf16_t* __restrict__ A,
                                          const bf16_t* __restrict__ Bm,
                                          const float*  __restrict__ bias,
                                          const float*  __restrict__ mask,
                                          void* __restrict__ Cout, int tile) {
  char* lsA = sm;
  char* lsB = sm + 16384;
  const int tid  = threadIdx.x;
  const int lane = tid & 63;
  const int wv   = tid >> 6;
  const int wm   = wv >> 1, wn = wv & 1;
  const int m0   = (tile >> 3) << 7;   // 32 m-tiles
  const int n0   = (tile & 7)  << 7;   // 8 n-tiles
  const int l15  = lane & 15;
  const int g16  = (lane >> 4) << 4;   // k-group byte base

  f32x4 acc[4][4] = {};

  for (int kk = 0; kk < MD; kk += 64) {
#pragma unroll
    for (int i = 0; i < 4; ++i) {
      int ch  = (wv << 2) + i;
      int o   = ch * 1024 + (lane << 4);
      int row = o >> 7;
      int scb = (o & 127) ^ ((row & 7) << 4);   // pre-swizzled source column byte
      const char* gA = (const char*)A  + (((size_t)(m0 + row) * MD + kk) << 1) + scb;
      const char* gB = (const char*)Bm + (((size_t)(n0 + row) * MD + kk) << 1) + scb;
      gload_lds16(gA, lsA + ch * 1024);
      gload_lds16(gB, lsB + ch * 1024);
    }
    __syncthreads();
#pragma unroll
    for (int s = 0; s < 2; ++s) {
      bf16x8 af[4], bfv[4];
#pragma unroll
      for (int mi = 0; mi < 4; ++mi) {
        int r  = (wm << 6) + (mi << 4) + l15;
        int cb = (g16 + (s << 6)) ^ ((r & 7) << 4);
        af[mi] = *(const bf16x8*)(lsA + (r << 7) + cb);
      }
#pragma unroll
      for (int ni = 0; ni < 4; ++ni) {
        int r  = (wn << 6) + (ni << 4) + l15;
        int cb = (g16 + (s << 6)) ^ ((r & 7) << 4);
        bfv[ni] = *(const bf16x8*)(lsB + (r << 7) + cb);
      }
      __builtin_amdgcn_s_setprio(1);
#pragma unroll
      for (int mi = 0; mi < 4; ++mi)
#pragma unroll
        for (int ni = 0; ni < 4; ++ni)
          acc[mi][ni] = __builtin_amdgcn_mfma_f32_16x16x32_bf16(af[mi], bfv[ni], acc[mi][ni], 0, 0, 0);
      __builtin_amdgcn_s_setprio(0);
    }
    __syncthreads();
  }

  // epilogue: C/D layout col = lane&15, row = (lane>>4)*4 + reg
  float bvv[4];
#pragma unroll
  for (int ni = 0; ni < 4; ++ni) bvv[ni] = bias[n0 + (wn << 6) + (ni << 4) + l15];
#pragma unroll
  for (int mi = 0; mi < 4; ++mi) {
    int m = m0 + (wm << 6) + (mi << 4) + ((lane >> 4) << 2);  // token rows m..m+3
    float4 mk = {1.0f, 1.0f, 1.0f, 1.0f};
    if constexpr (MODE == 2 || MODE == 3) mk = *(const float4*)&mask[m];
    if constexpr (MODE == 0) { if (mask) mk = *(const float4*)&mask[m]; }
#pragma unroll
    for (int ni = 0; ni < 4; ++ni) {
      int col = n0 + (wn << 6) + (ni << 4) + l15;
      if constexpr (MODE == 2) {
        // V PV-B-frag layout; 4 consecutive kv -> 4 contiguous elems (8B store)
        int b2 = m >> 11; int kv = m & 2047;
        int hh = col >> 6; int dd = col & 63;
        int dl = (dd >> 5) & 1; int dcol = dd & 31;
        size_t base = (size_t)((b2 << 4) + hh) * 131072 + (size_t)(kv >> 5) * 2048
                    + (size_t)((((kv >> 4) & 1) << 1) + dl) * 512
                    + (size_t)((((kv >> 3) & 1) << 5) + dcol) * 8 + (kv & 7);
        ushort4 pk;
        pk.x = f2bf((acc[mi][ni][0] + bvv[ni]) * mk.x);
        pk.y = f2bf((acc[mi][ni][1] + bvv[ni]) * mk.y);
        pk.z = f2bf((acc[mi][ni][2] + bvv[ni]) * mk.z);
        pk.w = f2bf((acc[mi][ni][3] + bvv[ni]) * mk.w);
        *(ushort4*)((unsigned short*)Cout + base) = pk;
      } else if constexpr (MODE == 3) {
        // K QKt-A-frag layout; 4 consecutive kv -> stride-8 scalar stores
        int b2 = m >> 11; int kv = m & 2047;
        int hh = col >> 6; int dd = col & 63;
        size_t base = (size_t)((b2 << 4) + hh) * 131072 + (size_t)(kv >> 5) * 2048
                    + (size_t)(dd >> 4) * 512
                    + (size_t)((((dd >> 3) & 1) << 5) + (kv & 31)) * 8 + (dd & 7);
#pragma unroll
        for (int r = 0; r < 4; ++r)
          ((unsigned short*)Cout)[base + ((size_t)r << 3)] =
              f2bf((acc[mi][ni][r] + bvv[ni]) * ((const float*)&mk)[r]);
      } else {
#pragma unroll
        for (int r = 0; r < 4; ++r) {
          float vv = acc[mi][ni][r] + bvv[ni];
          if constexpr (MODE == 0) vv *= ((const float*)&mk)[r];
          if constexpr (MODE == 1) ((float*)Cout)[(size_t)(m + r) * MD + col] = vv;
          else                     ((bf16_t*)Cout)[(size_t)(m + r) * MD + col] = (bf16_t)vv;
        }
      }
    }
  }
}

// fused QKV (768 blocks = 3/CU): Q row-major pre-scaled; K -> Kf frags; V -> Vf frags.
// ONE shared buffer for all three instantiations (32KB total).
__global__ __launch_bounds__(256, 3)
void gemm_qkv(const bf16_t* __restrict__ xq, const bf16_t* __restrict__ xk, const bf16_t* __restrict__ xv,
              const bf16_t* __restrict__ wq, const bf16_t* __restrict__ wk, const bf16_t* __restrict__ wv_,
              const float* __restrict__ bqs, const float* __restrict__ bk, const float* __restrict__ bv,
              const float* __restrict__ mask,
              bf16_t* __restrict__ Qo, bf16_t* __restrict__ Kfo, bf16_t* __restrict__ Vfo) {
  __shared__ __align__(1024) char sm[32768];
  int t = blockIdx.x & 255;
  int g = blockIdx.x >> 8;
  if (g == 0)      gemm_body<0>(sm, xq, wq,  bqs, nullptr, Qo,  t);
  else if (g == 1) gemm_body<3>(sm, xk, wk,  bk,  mask,    Kfo, t);
  else             gemm_body<2>(sm, xv, wv_, bv,  mask,    Vfo, t);
}

// output projection, 64x128 tiles -> 512 blocks = 2 blocks/CU (old 128x128
// grid was 256 blocks = 1 block/CU, zero inter-block overlap).
// 4 waves each cover 64m x 32n (acc[4][2]). A-tile 8KB + B-tile 16KB = 24KB.
__global__ __launch_bounds__(256, 2)
void gemm_out64(const bf16_t* __restrict__ A, const bf16_t* __restrict__ Bm,
                const float* __restrict__ bias, float* __restrict__ C) {
  __shared__ __align__(1024) char sm[24576];
  char* lsA = sm;           // 64 rows x 128B
  char* lsB = sm + 8192;    // 128 rows x 128B
  const int tile = (int)blockIdx.x;
  const int m0   = (tile >> 3) << 6;   // 64 m-tiles
  const int n0   = (tile & 7)  << 7;   // 8 n-tiles
  const int tid  = threadIdx.x;
  const int lane = tid & 63;
  const int wv   = tid >> 6;
  const int l15  = lane & 15;
  const int g16  = (lane >> 4) << 4;

  f32x4 acc[4][2] = {};

  for (int kk = 0; kk < MD; kk += 64) {
#pragma unroll
    for (int i = 0; i < 6; ++i) {
      int ch = wv * 6 + i;             // 24 chunks: 0-7 A, 8-23 B
      if (ch < 8) {
        int o   = ch * 1024 + (lane << 4);
        int row = o >> 7;
        int scb = (o & 127) ^ ((row & 7) << 4);
        gload_lds16((const char*)A + (((size_t)(m0 + row) * MD + kk) << 1) + scb,
                    lsA + ch * 1024);
      } else {
        int cl  = ch - 8;
        int o   = cl * 1024 + (lane << 4);
        int row = o >> 7;
        int scb = (o & 127) ^ ((row & 7) << 4);
        gload_lds16((const char*)Bm + (((size_t)(n0 + row) * MD + kk) << 1) + scb,
                    lsB + cl * 1024);
      }
    }
    __syncthreads();
#pragma unroll
    for (int s = 0; s < 2; ++s) {
      bf16x8 af[4], bfv[2];
#pragma unroll
      for (int mi = 0; mi < 4; ++mi) {
        int r  = (mi << 4) + l15;
        int cb = (g16 + (s << 6)) ^ ((r & 7) << 4);
        af[mi] = *(const bf16x8*)(lsA + (r << 7) + cb);
      }
#pragma unroll
      for (int ni = 0; ni < 2; ++ni) {
        int r  = (wv << 5) + (ni << 4) + l15;
        int cb = (g16 + (s << 6)) ^ ((r & 7) << 4);
        bfv[ni] = *(const bf16x8*)(lsB + (r << 7) + cb);
      }
      __builtin_amdgcn_s_setprio(1);
#pragma unroll
      for (int mi = 0; mi < 4; ++mi)
#pragma unroll
        for (int ni = 0; ni < 2; ++ni)
          acc[mi][ni] = __builtin_amdgcn_mfma_f32_16x16x32_bf16(af[mi], bfv[ni], acc[mi][ni], 0, 0, 0);
      __builtin_amdgcn_s_setprio(0);
    }
    __syncthreads();
  }

  float bvv[2];
#pragma unroll
  for (int ni = 0; ni < 2; ++ni) bvv[ni] = bias[n0 + (wv << 5) + (ni << 4) + l15];
#pragma unroll
  for (int mi = 0; mi < 4; ++mi) {
    int m = m0 + (mi << 4) + ((lane >> 4) << 2);
#pragma unroll
    for (int ni = 0; ni < 2; ++ni) {
      int col = n0 + (wv << 5) + (ni << 4) + l15;
#pragma unroll
      for (int r = 0; r < 4; ++r)
        C[(size_t)(m + r) * MD + col] = acc[mi][ni][r] + bvv[ni];
    }
  }
}

// ---------------- flash attention: all-fragment 32x32, zero LDS/barriers ----
// R18 structure EXACTLY (48.2us measured; R19's manual interleave regressed):
// grid 512 = b(2)*h(16)*qtile(16 of 128q), XCD swizzle; block 256 = 4 waves,
// each wave owns 32 q and sweeps ALL kv in 64 chunks of 32 (convoyed waves
// share L1). Ping-pong prefetch one chunk ahead; compiler schedules the
// interleave. Swapped QK^T: softmax lane-local (no-max builtin v_exp_f32,
// deferred reduce). P assembled in regs via cvt_pk + permlane32_swap.
__global__ __launch_bounds__(256, 2)
void attn_kernel(const bf16_t* __restrict__ Q, const bf16_t* __restrict__ Kf,
                 const bf16_t* __restrict__ Vf, const float* __restrict__ nmask,
                 bf16_t* __restrict__ O) {
  int bid = (int)blockIdx.x;
  int lb  = (bid & 7) * 64 + (bid >> 3);   // 512 = 8 x 64, bijective
  const int tid  = threadIdx.x;
  const int lane = tid & 63;
  const int w    = tid >> 6;
  const int qt   = lb & 15;
  const int h    = (lb >> 4) & 15;
  const int b    = lb >> 8;
  const int q0w  = (qt << 7) + (w << 5);
  const int l31  = lane & 31;
  const int hi   = lane >> 5;

  // Q B-frags: lane holds Q[q=l31][d = s4*16 + hi*8 + j]
  bf16x8 qa[4];
  {
    const bf16_t* qp = Q + (size_t)(b * SEQL + q0w + l31) * MD + h * HDIM + (hi << 3);
#pragma unroll
    for (int s4 = 0; s4 < 4; ++s4) qa[s4] = *(const bf16x8*)(qp + (s4 << 4));
  }

  const bf16_t* KfB = Kf + (size_t)((b << 4) + h) * 131072;
  const bf16_t* VfB = Vf + (size_t)((b << 4) + h) * 131072;

  f32x16 oacc0 = {};   // d 0-31
  f32x16 oacc1 = {};   // d 32-63
  float lrun = 0.0f;

  bf16x8 kA[4], vA[4], kB[4], vB[4];

  auto LDKV = [&](int c, bf16x8* kf, bf16x8* vf) {
    const bf16_t* kp = KfB + (size_t)c * 2048 + (lane << 3);
    const bf16_t* vp = VfB + (size_t)c * 2048 + (lane << 3);
#pragma unroll
    for (int s4 = 0; s4 < 4; ++s4) kf[s4] = *(const bf16x8*)(kp + (s4 << 9));
#pragma unroll
    for (int u = 0; u < 4; ++u)   vf[u] = *(const bf16x8*)(vp + (u << 9));
  };

  auto BLK = [&](bf16x8* kf, bf16x8* vf) {
    f32x16 sacc = {};
    __builtin_amdgcn_s_setprio(1);
#pragma unroll
    for (int s4 = 0; s4 < 4; ++s4)
      sacc = __builtin_amdgcn_mfma_f32_32x32x16_bf16(kf[s4], qa[s4], sacc, 0, 0, 0);
    __builtin_amdgcn_s_setprio(0);
    float e[16];
#pragma unroll
    for (int r = 0; r < 16; ++r) e[r] = FEXP2(sacc[r]);
    lrun += ((e[0] + e[1]) + (e[2] + e[3])) + ((e[4] + e[5]) + (e[6] + e[7]))
          + ((e[8] + e[9]) + (e[10] + e[11])) + ((e[12] + e[13]) + (e[14] + e[15]));
    // P -> PV A-frags (kv 0-15 and 16-31) via cvt_pk + permlane32_swap
    unsigned x1 = cvtpk(e[0], e[1]),  x2 = cvtpk(e[2], e[3]);
    unsigned y1 = cvtpk(e[4], e[5]),  y2 = cvtpk(e[6], e[7]);
    unsigned z1 = cvtpk(e[8], e[9]),  z2 = cvtpk(e[10], e[11]);
    unsigned w1 = cvtpk(e[12], e[13]), w2 = cvtpk(e[14], e[15]);
    asm("v_permlane32_swap_b32 %0, %1" : "+v"(x1), "+v"(y1));
    asm("v_permlane32_swap_b32 %0, %1" : "+v"(x2), "+v"(y2));
    asm("v_permlane32_swap_b32 %0, %1" : "+v"(z1), "+v"(w1));
    asm("v_permlane32_swap_b32 %0, %1" : "+v"(z2), "+v"(w2));
    union { unsigned u[4]; bf16x8 v; } p0, p1;
    p0.u[0] = x1; p0.u[1] = x2; p0.u[2] = y1; p0.u[3] = y2;
    p1.u[0] = z1; p1.u[1] = z2; p1.u[2] = w1; p1.u[3] = w2;
    __builtin_amdgcn_s_setprio(1);
    oacc0 = __builtin_amdgcn_mfma_f32_32x32x16_bf16(p0.v, vf[0], oacc0, 0, 0, 0);
    oacc1 = __builtin_amdgcn_mfma_f32_32x32x16_bf16(p0.v, vf[1], oacc1, 0, 0, 0);
    oacc0 = __builtin_amdgcn_mfma_f32_32x32x16_bf16(p1.v, vf[2], oacc0, 0, 0, 0);
    oacc1 = __builtin_amdgcn_mfma_f32_32x32x16_bf16(p1.v, vf[3], oacc1, 0, 0, 0);
    __builtin_amdgcn_s_setprio(0);
  };

  LDKV(0, kA, vA);
  for (int ii = 0; ii < 32; ++ii) {
    LDKV((ii << 1) + 1, kB, vB);
    BLK(kA, vA);
    LDKV((ii << 1) + 2, kA, vA);   // ii=31 reads pad block 64 (harmless)
    BLK(kB, vB);
  }

  // epilogue: combine hi halves of lrun, normalize, store O (row-major bf16)
  lrun += __shfl_xor(lrun, 32);
  float linv = 1.0f / (lrun - nmask[b]);
#pragma unroll
  for (int r = 0; r < 16; ++r) {
    int q = (r & 3) + ((r >> 2) << 3) + (hi << 2);
    float lr = __shfl(linv, q);
    size_t ro = (size_t)(b * SEQL + q0w + q) * MD + h * HDIM;
    O[ro + l31]      = (bf16_t)(oacc0[r] * lr);
    O[ro + 32 + l31] = (bf16_t)(oacc1[r] * lr);
  }
}

// ---------------- launch ----------------
extern "C" void kernel_launch(void* const* d_in, const int* in_sizes, int n_in,
                              void* d_out, int out_size, void* d_ws, size_t ws_size,
                              hipStream_t stream) {
  const float* in_k = (const float*)d_in[0];
  const float* in_q = (const float*)d_in[1];
  const float* in_v = (const float*)d_in[2];
  const float* mask = (const float*)d_in[3];
  const float* Wq   = (const float*)d_in[4];
  const float* bq   = (const float*)d_in[5];
  const float* Wk   = (const float*)d_in[6];
  const float* bk   = (const float*)d_in[7];
  const float* Wv   = (const float*)d_in[8];
  const float* bv   = (const float*)d_in[9];
  const float* Wo   = (const float*)d_in[10];
  const float* bo   = (const float*)d_in[11];

  const size_t XN = (size_t)MROWS * MD;   // 4,194,304 elems
  const size_t WN = (size_t)MD * MD;      // 1,048,576 elems
  char* w = (char*)d_ws;
  size_t off = 0;
  auto alloc = [&](size_t bytes) { char* p = w + off; off += bytes; return p; };
  bf16_t* xq    = (bf16_t*)alloc(XN * 2);
  bf16_t* xk    = (bf16_t*)alloc(XN * 2);
  bf16_t* xv    = (bf16_t*)alloc(XN * 2);
  bf16_t* wqb   = (bf16_t*)alloc(WN * 2);
  bf16_t* wkb   = (bf16_t*)alloc(WN * 2);
  bf16_t* wvb   = (bf16_t*)alloc(WN * 2);
  bf16_t* wob   = (bf16_t*)alloc(WN * 2);
  bf16_t* Qp    = (bf16_t*)alloc(XN * 2);
  bf16_t* Kfp   = (bf16_t*)alloc(XN * 2 + 8192);   // + pad for prefetch overrun
  bf16_t* Vfp   = (bf16_t*)alloc(XN * 2 + 8192);
  float*  bqs   = (float*)alloc(MD * 4);
  float*  nmask = (float*)alloc(16);
  bf16_t* attn  = xq;  // alias: xq is dead after gemm_qkv
  (void)ws_size;

  // single consolidated convert (3 X + 4 W + bqs + nmask)
  cvt_all<<<16387, 256, 0, stream>>>(in_q, in_k, in_v, Wq, Wk, Wv, Wo, mask, bq,
                                     (unsigned short*)xq, (unsigned short*)xk, (unsigned short*)xv,
                                     (unsigned short*)wqb, (unsigned short*)wkb,
                                     (unsigned short*)wvb, (unsigned short*)wob, bqs, nmask);

  // fused QKV projection; K/V written in MFMA fragment layouts
  gemm_qkv<<<768, 256, 0, stream>>>(xq, xk, xv, wqb, wkb, wvb, bqs, bk, bv, mask, Qp, Kfp, Vfp);

  // flash attention: 512 blocks x 4 waves x 32 q, all-fragment, no LDS
  attn_kernel<<<512, 256, 0, stream>>>(Qp, Kfp, Vfp, nmask, attn);

  // output projection -> fp32 d_out (64x128 tiles, 2 blocks/CU)
  gemm_out64<<<512, 256, 0, stream>>>(attn, wob, bo, (float*)d_out);
}